// Round 4
// baseline (348.758 us; speedup 1.0000x reference)
//
#include <hip/hip_runtime.h>
#include <cstdint>
#include <cstddef>

// (B,H,L,D,k) = (4,1,2048,512,4), SHIFTS = {1,2,4}
// Folded: out[(b,l,j),d] = sum_c v[c]*Qj[c,d]               (diff, K=512)
//                        + sum_{si,c} silu(v[c]*W[j,(c-s)%512]) * Psilu[si,c,d]  (K=1536)
// v = x[b,l-1] for j<3, x[b,l] for j==3.
// Round 4: K-loop is barrier-free — A and B fragments loaded global->VGPR
// directly (per-lane MFMA fragment addressing), 2-deep register pipeline.
// No LDS in the hot kernel -> no vmcnt(0) barrier drain on the GS HBM stream.
#define D_DIM 512
#define L_DIM 2048
#define KB_DIM 2048    // 512 diff + 3*512 silu
#define KS_DIM 1536
#define NROWS_X 2049   // per-b rows in XbfZ; row 0 is zeros (the l=-1 pad)
#define M_TOT 32768

typedef __bf16 bf16x8 __attribute__((ext_vector_type(8)));
typedef float  f32x4  __attribute__((ext_vector_type(4)));

__device__ __forceinline__ unsigned f2bf(float f) {
  unsigned u = __float_as_uint(f);
  u += 0x7FFF + ((u >> 16) & 1);   // RNE
  return u >> 16;
}
__device__ __forceinline__ float bf2f(unsigned short u) {
  return __uint_as_float(((unsigned)u) << 16);
}
__device__ __forceinline__ void gld_lds16(const void* g, void* l) {
  __builtin_amdgcn_global_load_lds((const __attribute__((address_space(1))) void*)g,
                                   (__attribute__((address_space(3))) void*)l,
                                   16, 0, 0);
}

// ---------------- prepass 1: x fp32 -> XbfZ bf16 with per-b zero row at index 0 ----
__global__ void convert_x(const float* __restrict__ x, unsigned short* __restrict__ XbfZ) {
  const int b = blockIdx.y;
  const int idx = blockIdx.x * 256 + threadIdx.x;   // over 2049*128 uint2-groups
  if (idx >= NROWS_X * 128) return;
  const int rr = idx >> 7;       // 0..2048 ; rr==0 -> zero row
  const int c4 = idx & 127;
  uint2 p = {0u, 0u};
  if (rr > 0) {
    float4 v = reinterpret_cast<const float4*>(x)[((size_t)b * L_DIM + rr - 1) * 128 + c4];
    p.x = f2bf(v.x) | (f2bf(v.y) << 16);
    p.y = f2bf(v.z) | (f2bf(v.w) << 16);
  }
  reinterpret_cast<uint2*>(XbfZ)[((size_t)b * NROWS_X + rr) * 128 + c4] = p;
}

// ---------------- prepass 2: build Ball[j][d][k] bf16 (k-major rows) + Wtab ----------
__global__ void build_B(const float* __restrict__ P, const float* __restrict__ W,
                        unsigned short* __restrict__ Ball,
                        unsigned short* __restrict__ Wtab, int buildWtab) {
  if (buildWtab && blockIdx.x == 0) {
    for (int i = threadIdx.x; i < 6144; i += 256) {
      const int c = i & 511; const int rest = i >> 9;
      const int si = rest % 3; const int jj = rest / 3;
      Wtab[(jj * 3 + si) * 512 + c] =
          (unsigned short)f2bf(W[jj * 512 + ((c - (1 << si)) & 511)]);
    }
  }
  const int bx = blockIdx.x;             // 256 blocks
  const int j = bx >> 6, dt = (bx >> 3) & 7, ct = bx & 7;
  const int t = threadIdx.x;
  const int d = dt * 64 + (t & 63);
  const int cbase = ct * 64 + (t >> 6) * 16;
  unsigned short bufd[16];
  unsigned short bufs[3][16];
  #pragma unroll
  for (int cc = 0; cc < 16; ++cc) {
    const int c = cbase + cc;
    float qd = 0.f;
    #pragma unroll
    for (int si = 0; si < 3; ++si) {
      const int s = 1 << si;
      const int cm = (c - s) & 511, cp = (c + s) & 511;
      qd += W[j * 512 + cm] * P[((size_t)(2 * si) * 512 + c) * 512 + d]
          - W[j * 512 + cp] * P[((size_t)(2 * si) * 512 + cp) * 512 + d];
      bufs[si][cc] = (unsigned short)f2bf(P[((size_t)(2 * si + 1) * 512 + c) * 512 + d]);
    }
    bufd[cc] = (unsigned short)f2bf(qd);
  }
  unsigned short* row = Ball + (size_t)(j * 512 + d) * KB_DIM;
  *reinterpret_cast<uint4*>(&row[cbase])     = *reinterpret_cast<uint4*>(&bufd[0]);
  *reinterpret_cast<uint4*>(&row[cbase + 8]) = *reinterpret_cast<uint4*>(&bufd[8]);
  #pragma unroll
  for (int si = 0; si < 3; ++si) {
    *reinterpret_cast<uint4*>(&row[512 + si * 512 + cbase])     = *reinterpret_cast<uint4*>(&bufs[si][0]);
    *reinterpret_cast<uint4*>(&row[512 + si * 512 + cbase + 8]) = *reinterpret_cast<uint4*>(&bufs[si][8]);
  }
}

// ---------------- prepass 3: materialize silu A: GS[(j,b,l)][si*512+c] bf16 ----------
__global__ void gs_gen(const unsigned short* __restrict__ XbfZ,
                       const unsigned short* __restrict__ Wtab,
                       unsigned short* __restrict__ GS) {
  const int m0 = blockIdx.x * 4;          // 8192 blocks, 4 rows each
  const int j = m0 >> 13, b = (m0 >> 11) & 3, lbase = m0 & 2047;
  const int r = threadIdx.x >> 6, lane = threadIdx.x & 63;
  const int l = lbase + r;
  const size_t vrow = (size_t)b * NROWS_X + l + (j == 3);
  union U { uint4 q; unsigned short s[8]; };
  U va;
  va.q = *reinterpret_cast<const uint4*>(XbfZ + vrow * 512 + lane * 8);
  unsigned short* o = GS + (size_t)(m0 + r) * KS_DIM + lane * 8;
  #pragma unroll
  for (int si = 0; si < 3; ++si) {
    U wa;
    wa.q = *reinterpret_cast<const uint4*>(Wtab + (j * 3 + si) * 512 + lane * 8);
    unsigned res[4];
    #pragma unroll
    for (int e = 0; e < 4; ++e) {
      float s0 = bf2f(va.s[2 * e])     * bf2f(wa.s[2 * e]);
      float s1 = bf2f(va.s[2 * e + 1]) * bf2f(wa.s[2 * e + 1]);
      float g0 = s0 * __builtin_amdgcn_rcpf(1.f + __expf(-s0));
      float g1 = s1 * __builtin_amdgcn_rcpf(1.f + __expf(-s1));
      res[e] = f2bf(g0) | (f2bf(g1) << 16);
    }
    uint4 ov = {res[0], res[1], res[2], res[3]};
    *reinterpret_cast<uint4*>(o + si * 512) = ov;
  }
}

// ---------------- main GEMM: barrier-free, all-register fragments ----------------
__global__ __launch_bounds__(256) void gemm_main(
    const unsigned short* __restrict__ XbfZ, const unsigned short* __restrict__ GS,
    const unsigned short* __restrict__ Ball, const float* __restrict__ bias,
    float* __restrict__ out) {
  const int tid = threadIdx.x;
  const int bx = blockIdx.x;
  const int nt = bx >> 8;                // contiguous bx share (j,nt) -> L2 locality for B
  const int mt = bx & 255;
  const int j  = mt >> 6;
  const int b  = (mt >> 4) & 3;
  const int l0 = (mt & 15) * 128;
  const int n0 = nt * 128;

  // ---- MFMA fragment geometry: 4 waves 2x2, wave-tile 64x64 ----
  const int lane = tid & 63, wv = tid >> 6;
  const int wm = wv >> 1, wn = wv & 1;
  const int l16 = lane & 15, quad = lane >> 4;

  // per-lane fragment source pointers
  // A diff (it 0..15): XbfZ row b*2049 + l0 + (j==3) + wm*64 + mi*16 + l16, k = it*32 + quad*8
  const unsigned short* pA[4];
  {
    const unsigned short* base =
        XbfZ + ((size_t)b * NROWS_X + l0 + (j == 3) + wm * 64 + l16) * 512 + quad * 8;
    #pragma unroll
    for (int mi = 0; mi < 4; ++mi) pA[mi] = base + (size_t)mi * 16 * 512;
  }
  // A silu source (it 16..63): GS row (j*4+b)*2048 + l0 + wm*64 + mi*16 + l16
  const unsigned short* pAg =
      GS + ((size_t)((j * 4 + b) * L_DIM + l0 + wm * 64 + l16)) * KS_DIM + quad * 8;
  // B: Ball row j*512 + n0 + wn*64 + ni*16 + l16, k advances 32/iter over 2048
  const unsigned short* pB[4];
  {
    const unsigned short* base =
        Ball + ((size_t)(j * 512 + n0 + wn * 64 + l16)) * KB_DIM + quad * 8;
    #pragma unroll
    for (int ni = 0; ni < 4; ++ni) pB[ni] = base + (size_t)ni * 16 * KB_DIM;
  }

  f32x4 acc[4][4];
  #pragma unroll
  for (int i = 0; i < 4; ++i)
    #pragma unroll
    for (int n = 0; n < 4; ++n)
      acc[i][n] = f32x4{0.f, 0.f, 0.f, 0.f};

  uint4 aE[4], bE[4], aO[4], bO[4];

#define LOAD_SET(aset, bset)                                         \
  do {                                                               \
    _Pragma("unroll")                                                \
    for (int mi = 0; mi < 4; ++mi) {                                 \
      aset[mi] = *reinterpret_cast<const uint4*>(pA[mi]);            \
      pA[mi] += 32;                                                  \
    }                                                                \
    _Pragma("unroll")                                                \
    for (int ni = 0; ni < 4; ++ni) {                                 \
      bset[ni] = *reinterpret_cast<const uint4*>(pB[ni]);            \
      pB[ni] += 32;                                                  \
    }                                                                \
  } while (0)

#define MFMA_SET(aset, bset)                                         \
  do {                                                               \
    _Pragma("unroll")                                                \
    for (int mi = 0; mi < 4; ++mi) {                                 \
      bf16x8 af = __builtin_bit_cast(bf16x8, aset[mi]);              \
      _Pragma("unroll")                                              \
      for (int ni = 0; ni < 4; ++ni) {                               \
        bf16x8 bf = __builtin_bit_cast(bf16x8, bset[ni]);            \
        acc[mi][ni] =                                                \
            __builtin_amdgcn_mfma_f32_16x16x32_bf16(af, bf, acc[mi][ni], 0, 0, 0); \
      }                                                              \
    }                                                                \
  } while (0)

  LOAD_SET(aE, bE);                      // it = 0
  for (int h = 0; h < 32; ++h) {
    LOAD_SET(aO, bO);                    // it = 2h+1
    MFMA_SET(aE, bE);                    // it = 2h
    if (h == 7) {                        // next even load is it=16 -> switch A to GS
      #pragma unroll
      for (int mi = 0; mi < 4; ++mi) pA[mi] = pAg + (size_t)mi * 16 * KS_DIM;
    }
    if (h < 31) LOAD_SET(aE, bE);        // it = 2h+2
    MFMA_SET(aO, bO);                    // it = 2h+1
  }
#undef LOAD_SET
#undef MFMA_SET

  // ---- epilogue: C/D col = lane&15 (N), row = quad*4+reg (M) ----
  #pragma unroll
  for (int ni = 0; ni < 4; ++ni) {
    const int d = n0 + wn * 64 + ni * 16 + l16;
    const float bv = bias[d];
    #pragma unroll
    for (int mi = 0; mi < 4; ++mi) {
      const int lrow = l0 + wm * 64 + mi * 16 + quad * 4;
      #pragma unroll
      for (int rg = 0; rg < 4; ++rg) {
        out[((size_t)(b * L_DIM + lrow + rg) * 4 + j) * D_DIM + d] = acc[mi][ni][rg] + bv;
      }
    }
  }
}

// ---------------- fallback: round-2 fused kernel (used if ws too small) ----------------
__global__ __launch_bounds__(256, 2) void fused_gemm(
    const unsigned short* __restrict__ XbfZ, const unsigned short* __restrict__ Ball,
    const float* __restrict__ W, const float* __restrict__ bias,
    float* __restrict__ out) {
  __shared__ alignas(16) unsigned short Vt[2][4096];
  __shared__ alignas(16) unsigned short Bt[2][8192];
  __shared__ alignas(16) unsigned short At[128 * 40];
  __shared__ alignas(16) unsigned short Wr[3 * 512];

  const int tid = threadIdx.x;
  const int nt = blockIdx.x & 1;
  const int mt = blockIdx.x >> 1;
  const int j  = mt >> 6;
  const int b  = (mt >> 4) & 3;
  const int lt = mt & 15;
  const int l0 = lt * 128;
  const int n0 = nt * 256;
  const int base_l = l0 - ((j == 3) ? 0 : 1);

  #pragma unroll
  for (int i = 0; i < 6; ++i) {
    const int idx = tid + i * 256;
    const int si = idx >> 9, c = idx & 511, s = 1 << si;
    Wr[idx] = (unsigned short)f2bf(W[j * 512 + ((c - s) & 511)]);
  }

  const int lane = tid & 63, wv = tid >> 6;
  const int qv = (lane & 3) ^ ((lane >> 4) & 3);
  const int rsub = lane >> 2;
  const unsigned short* gA0 = XbfZ + ((size_t)(b * NROWS_X + 1 + base_l + (wv * 2) * 16 + rsub)) * 512 + qv * 8;
  const unsigned short* gA1 = gA0 + (size_t)16 * 512;
  const unsigned short* gB[4];
  #pragma unroll
  for (int pi = 0; pi < 4; ++pi)
    gB[pi] = Ball + (size_t)(j * 512 + n0 + (wv * 4 + pi) * 16 + rsub) * KB_DIM + qv * 8;
  const int vOff0 = wv * 1024 + lane * 8;
  const int bOff0 = wv * 2048 + lane * 8;

  const int am = tid >> 1;
  const int akh = (tid & 1) * 16;
  const int ch0 = (tid & 1) * 2;
  const int sswz = (am >> 2) & 3;
  unsigned short* aDst = &At[am * 40 + akh];

  const int l16 = lane & 15, quad = lane >> 4;
  const int wm = wv >> 1, wn = wv & 1;
  const int fsw = (l16 >> 2) & 3;
  const int aVoff = (wm * 64 + l16) * 32 + ((quad ^ fsw)) * 8;
  const int aSoff = (wm * 64 + l16) * 40 + quad * 8;
  const int bOffF = (wn * 128 + l16) * 32 + ((quad ^ fsw)) * 8;

  f32x4 acc[4][8];
  #pragma unroll
  for (int i = 0; i < 4; ++i)
    #pragma unroll
    for (int n = 0; n < 8; ++n)
      acc[i][n] = f32x4{0.f, 0.f, 0.f, 0.f};

  {
    gld_lds16(gA0, &Vt[0][vOff0]);
    gld_lds16(gA1, &Vt[0][vOff0 + 512]);
    #pragma unroll
    for (int pi = 0; pi < 4; ++pi)
      gld_lds16(gB[pi], &Bt[0][bOff0 + pi * 512]);
  }

  for (int it = 0; it < 64; ++it) {
    const int buf = it & 1;
    const int kk0 = it * 32;
    const int gi = kk0 >> 9;

    __syncthreads();

    if (it + 1 < 64) {
      const int nk = kk0 + 32;
      const int nv = nk & 511;
      gld_lds16(gA0 + nv, &Vt[buf ^ 1][vOff0]);
      gld_lds16(gA1 + nv, &Vt[buf ^ 1][vOff0 + 512]);
      #pragma unroll
      for (int pi = 0; pi < 4; ++pi)
        gld_lds16(gB[pi] + nk, &Bt[buf ^ 1][bOff0 + pi * 512]);
    }

    bf16x8 af[4], bfr[8];
    if (gi == 0) {
      #pragma unroll
      for (int mi = 0; mi < 4; ++mi) {
        uint4 r = *reinterpret_cast<const uint4*>(&Vt[buf][aVoff + mi * 512]);
        af[mi] = __builtin_bit_cast(bf16x8, r);
      }
    } else {
      const int si = gi - 1;
      const int ccbase = (kk0 & 511) + akh;
      uint4 v0 = *reinterpret_cast<const uint4*>(&Vt[buf][(am * 4 + ((ch0)     ^ sswz)) * 8]);
      uint4 v1 = *reinterpret_cast<const uint4*>(&Vt[buf][(am * 4 + ((ch0 + 1) ^ sswz)) * 8]);
      uint4 w0 = *reinterpret_cast<const uint4*>(&Wr[si * 512 + ccbase]);
      uint4 w1 = *reinterpret_cast<const uint4*>(&Wr[si * 512 + ccbase + 8]);
      union U { uint4 q[2]; unsigned short s[16]; };
      U va, wa; va.q[0] = v0; va.q[1] = v1; wa.q[0] = w0; wa.q[1] = w1;
      unsigned res[8];
      #pragma unroll
      for (int e = 0; e < 8; ++e) {
        float s0 = bf2f(va.s[2 * e])     * bf2f(wa.s[2 * e]);
        float s1 = bf2f(va.s[2 * e + 1]) * bf2f(wa.s[2 * e + 1]);
        float g0 = s0 * __builtin_amdgcn_rcpf(1.f + __expf(-s0));
        float g1 = s1 * __builtin_amdgcn_rcpf(1.f + __expf(-s1));
        res[e] = f2bf(g0) | (f2bf(g1) << 16);
      }
      uint4 o0 = {res[0], res[1], res[2], res[3]};
      uint4 o1 = {res[4], res[5], res[6], res[7]};
      *reinterpret_cast<uint4*>(aDst) = o0;
      *reinterpret_cast<uint4*>(aDst + 8) = o1;
      __syncthreads();
      #pragma unroll
      for (int mi = 0; mi < 4; ++mi) {
        uint4 r = *reinterpret_cast<const uint4*>(&At[aSoff + mi * 640]);
        af[mi] = __builtin_bit_cast(bf16x8, r);
      }
    }
    #pragma unroll
    for (int ni = 0; ni < 8; ++ni) {
      uint4 r = *reinterpret_cast<const uint4*>(&Bt[buf][bOffF + ni * 512]);
      bfr[ni] = __builtin_bit_cast(bf16x8, r);
    }
    #pragma unroll
    for (int mi = 0; mi < 4; ++mi)
      #pragma unroll
      for (int ni = 0; ni < 8; ++ni)
        acc[mi][ni] = __builtin_amdgcn_mfma_f32_16x16x32_bf16(af[mi], bfr[ni], acc[mi][ni], 0, 0, 0);
  }

  #pragma unroll
  for (int ni = 0; ni < 8; ++ni) {
    const int d = n0 + wn * 128 + ni * 16 + l16;
    const float bv = bias[d];
    #pragma unroll
    for (int mi = 0; mi < 4; ++mi) {
      const int lrow = l0 + wm * 64 + mi * 16 + quad * 4;
      #pragma unroll
      for (int rg = 0; rg < 4; ++rg) {
        out[((size_t)(b * L_DIM + lrow + rg) * 4 + j) * D_DIM + d] = acc[mi][ni][rg] + bv;
      }
    }
  }
}

extern "C" void kernel_launch(void* const* d_in, const int* in_sizes, int n_in,
                              void* d_out, int out_size, void* d_ws, size_t ws_size,
                              hipStream_t stream) {
  const float* x    = (const float*)d_in[0];  // (4,1,2048,512) fp32
  const float* W    = (const float*)d_in[1];  // (4,512) fp32
  const float* P    = (const float*)d_in[2];  // (3072,512) fp32
  const float* bias = (const float*)d_in[3];  // (512,) fp32
  float* out = (float*)d_out;                 // (4,1,8192,512) fp32

  unsigned short* XbfZ = (unsigned short*)d_ws;                       // 4*2049*512   = 4,196,352 shorts
  unsigned short* Ball = XbfZ + (size_t)4 * NROWS_X * 512;            // 4*512*2048   = 4,194,304
  unsigned short* Wtab = Ball + (size_t)4 * 512 * KB_DIM;             // 6,144
  unsigned short* GS   = Wtab + 6144;                                 // 32768*1536   = 50,331,648
  const size_t need_bytes =
      ((size_t)4 * NROWS_X * 512 + (size_t)4 * 512 * KB_DIM + 6144 +
       (size_t)M_TOT * KS_DIM) * 2;
  const bool primary = ws_size >= need_bytes;

  convert_x<<<dim3(1025, 4), 256, 0, stream>>>(x, XbfZ);
  build_B<<<256, 256, 0, stream>>>(P, W, Ball, Wtab, primary ? 1 : 0);
  if (primary) {
    gs_gen<<<8192, 256, 0, stream>>>(XbfZ, Wtab, GS);
    gemm_main<<<1024, 256, 0, stream>>>(XbfZ, GS, Ball, bias, out);
  } else {
    fused_gemm<<<512, 256, 0, stream>>>(XbfZ, Ball, W, bias, out);
  }
}

// Round 5
// 208.616 us; speedup vs baseline: 1.6718x; 1.6718x over previous
//
#include <hip/hip_runtime.h>
#include <cstdint>
#include <cstddef>

// (B,H,L,D,k) = (4,1,2048,512,4), SHIFTS = {1,2,4}
// Folded: out[(b,l,j),d] = sum_c v[c]*Qj[c,d]               (diff, K=512)
//                        + sum_{si,c} silu(v[c]*W[j,(c-s)%512]) * Psilu[si,c,d]  (K=1536)
// v = x[b,l-1] for j<3, x[b,l] for j==3.
// Round 5: no GS matrix. Hot kernel stages only L2-resident tiles (v-slice, Ball)
// via global_load_lds issued AFTER the barrier (drain-free dbuf); silu A-fragments
// computed in registers per wave (M-strip partition -> each element once).
// 256-B-line XOR swizzle makes all LDS fragment reads 2-way (free).
#define D_DIM 512
#define L_DIM 2048
#define KB_DIM 2048    // 512 diff + 3*512 silu
#define NROWS_X 2049   // per-b rows in XbfZ; row 0 is zeros (the l=-1 pad)

typedef __bf16 bf16x8 __attribute__((ext_vector_type(8)));
typedef float  f32x4  __attribute__((ext_vector_type(4)));

__device__ __forceinline__ unsigned f2bf(float f) {
  unsigned u = __float_as_uint(f);
  u += 0x7FFF + ((u >> 16) & 1);   // RNE
  return u >> 16;
}
__device__ __forceinline__ void gld_lds16(const void* g, void* l) {
  __builtin_amdgcn_global_load_lds((const __attribute__((address_space(1))) void*)g,
                                   (__attribute__((address_space(3))) void*)l,
                                   16, 0, 0);
}

// ---------------- prepass 1: x fp32 -> XbfZ bf16 with per-b zero row at index 0 ----
__global__ void convert_x(const float* __restrict__ x, unsigned short* __restrict__ XbfZ) {
  const int b = blockIdx.y;
  const int idx = blockIdx.x * 256 + threadIdx.x;   // over 2049*128 uint2-groups
  if (idx >= NROWS_X * 128) return;
  const int rr = idx >> 7;       // 0..2048 ; rr==0 -> zero row
  const int c4 = idx & 127;
  uint2 p = {0u, 0u};
  if (rr > 0) {
    float4 v = reinterpret_cast<const float4*>(x)[((size_t)b * L_DIM + rr - 1) * 128 + c4];
    p.x = f2bf(v.x) | (f2bf(v.y) << 16);
    p.y = f2bf(v.z) | (f2bf(v.w) << 16);
  }
  reinterpret_cast<uint2*>(XbfZ)[((size_t)b * NROWS_X + rr) * 128 + c4] = p;
}

// ---------------- prepass 2: build Ball[j][d][k] bf16 (k-major rows) ----------------
// k in [0,512): Qj fold:  sum_si W[j,(c-s)]*P[2si*512+c][d] - W[j,(c+s)]*P[2si*512+(c+s)][d]
// k in [512+si*512, +512): Psilu: P[(2si+1)*512+c][d]
__global__ void build_B(const float* __restrict__ P, const float* __restrict__ W,
                        unsigned short* __restrict__ Ball) {
  const int bx = blockIdx.x;             // 256 blocks
  const int j = bx >> 6, dt = (bx >> 3) & 7, ct = bx & 7;
  const int t = threadIdx.x;
  const int d = dt * 64 + (t & 63);
  const int cbase = ct * 64 + (t >> 6) * 16;
  unsigned short bufd[16];
  unsigned short bufs[3][16];
  #pragma unroll
  for (int cc = 0; cc < 16; ++cc) {
    const int c = cbase + cc;
    float qd = 0.f;
    #pragma unroll
    for (int si = 0; si < 3; ++si) {
      const int s = 1 << si;
      const int cm = (c - s) & 511, cp = (c + s) & 511;
      qd += W[j * 512 + cm] * P[((size_t)(2 * si) * 512 + c) * 512 + d]
          - W[j * 512 + cp] * P[((size_t)(2 * si) * 512 + cp) * 512 + d];
      bufs[si][cc] = (unsigned short)f2bf(P[((size_t)(2 * si + 1) * 512 + c) * 512 + d]);
    }
    bufd[cc] = (unsigned short)f2bf(qd);
  }
  unsigned short* row = Ball + (size_t)(j * 512 + d) * KB_DIM;
  *reinterpret_cast<uint4*>(&row[cbase])     = *reinterpret_cast<uint4*>(&bufd[0]);
  *reinterpret_cast<uint4*>(&row[cbase + 8]) = *reinterpret_cast<uint4*>(&bufd[8]);
  #pragma unroll
  for (int si = 0; si < 3; ++si) {
    *reinterpret_cast<uint4*>(&row[512 + si * 512 + cbase])     = *reinterpret_cast<uint4*>(&bufs[si][0]);
    *reinterpret_cast<uint4*>(&row[512 + si * 512 + cbase + 8]) = *reinterpret_cast<uint4*>(&bufs[si][8]);
  }
}

// ---------------- main kernel ----------------
// LDS tile layout (per 128-row x 32-k tile, 8 KB): slot s in [0,512) of 16 B.
//   s -> row = 2*(s>>3) + ((s>>2)&1), chunk = (s&3) ^ ((s>>3)&3)   (chunk = 8 shorts of k)
// Read side: (row, chunkGlobal q) lives at line=(row>>1), pos=(q ^ (line&3)) + 4*(row&1),
//   addr(shorts) = line*64 + pos*8.  Fragment reads -> 2-way bank aliasing only (free).
__global__ __launch_bounds__(256, 4) void gemm_main(
    const unsigned short* __restrict__ XbfZ, const unsigned short* __restrict__ Ball,
    const float* __restrict__ W, const float* __restrict__ bias,
    float* __restrict__ out) {
  __shared__ alignas(16) unsigned short Vt[2][4096];   // 8 KB each
  __shared__ alignas(16) unsigned short Btl[2][4096];
  __shared__ alignas(16) float Wr[1536];               // rolled W[j], fp32

  const int tid = threadIdx.x;
  const int bx = blockIdx.x;
  const int nt = bx >> 8;                // 16 consecutive mt share (j,nt) -> L2
  const int mt = bx & 255;
  const int j  = mt >> 6;
  const int b  = (mt >> 4) & 3;
  const int l0 = (mt & 15) * 128;
  const int n0 = nt * 128;

  // ---- stage rolled W (fp32): Wr[si*512+c] = W[j, (c - 2^si) mod 512] ----
  #pragma unroll
  for (int i = 0; i < 6; ++i) {
    const int idx = tid + i * 256;
    const int si = idx >> 9, c = idx & 511;
    Wr[idx] = W[j * 512 + ((c - (1 << si)) & 511)];
  }

  // ---- staging geometry: thread covers slots tid and tid+256 (row+64, same chunk) ----
  const int row1   = 2 * (tid >> 3) + ((tid >> 2) & 1);
  const int chunk1 = (tid & 3) ^ ((tid >> 3) & 3);
  const unsigned short* srcV =
      XbfZ + ((size_t)b * NROWS_X + l0 + (j == 3) + row1) * 512 + chunk1 * 8;
  const unsigned short* srcB =
      Ball + ((size_t)(j * 512 + n0 + row1)) * KB_DIM + chunk1 * 8;

  // ---- fragment geometry: wave wv = M-strip rows [wv*32, wv*32+32), all 128 N ----
  const int lane = tid & 63, wv = tid >> 6;
  const int l16 = lane & 15, quad = lane >> 4;
  const int posf  = ((quad ^ ((l16 >> 1) & 3)) + 4 * (l16 & 1)) * 8;  // shorts
  const int aOff0 = (wv * 16 + (l16 >> 1)) * 64 + posf;   // + mi*512
  const int bOff0 = (l16 >> 1) * 64 + posf;               // + ni*512
  const int wOff  = quad * 8;

  f32x4 acc[2][8];
  #pragma unroll
  for (int i = 0; i < 2; ++i)
    #pragma unroll
    for (int n = 0; n < 8; ++n)
      acc[i][n] = f32x4{0.f, 0.f, 0.f, 0.f};

  // prologue: tile 0
  gld_lds16(srcV, &Vt[0][tid * 8]);
  gld_lds16(srcV + (size_t)64 * 512, &Vt[0][(tid + 256) * 8]);
  gld_lds16(srcB, &Btl[0][tid * 8]);
  gld_lds16(srcB + (size_t)64 * KB_DIM, &Btl[0][(tid + 256) * 8]);

  for (int it = 0; it < 64; ++it) {
    const int buf = it & 1;
    __syncthreads();   // drains tile(it)'s glds — issued one full compute phase ago
    if (it + 1 < 64) { // prefetch AFTER the barrier: lives across the whole compute phase
      const int kv = ((it + 1) * 32) & 511;
      const int kb = (it + 1) * 32;
      gld_lds16(srcV + kv, &Vt[buf ^ 1][tid * 8]);
      gld_lds16(srcV + (size_t)64 * 512 + kv, &Vt[buf ^ 1][(tid + 256) * 8]);
      gld_lds16(srcB + kb, &Btl[buf ^ 1][tid * 8]);
      gld_lds16(srcB + (size_t)64 * KB_DIM + kb, &Btl[buf ^ 1][(tid + 256) * 8]);
    }

    bf16x8 af[2];
    if (it < 16) {
      // diff group: A = v directly
      #pragma unroll
      for (int mi = 0; mi < 2; ++mi) {
        uint4 vr = *reinterpret_cast<const uint4*>(&Vt[buf][aOff0 + mi * 512]);
        af[mi] = __builtin_bit_cast(bf16x8, vr);
      }
    } else {
      // silu group si: A = silu(v * w), computed in registers (each element once)
      const int si = (it >> 4) - 1;
      const int kwin = (it * 32) & 511;
      const float* wp = &Wr[si * 512 + kwin + wOff];
      const float4 wa = *reinterpret_cast<const float4*>(wp);
      const float4 wb = *reinterpret_cast<const float4*>(wp + 4);
      const float wreg[8] = {wa.x, wa.y, wa.z, wa.w, wb.x, wb.y, wb.z, wb.w};
      #pragma unroll
      for (int mi = 0; mi < 2; ++mi) {
        uint4 vr = *reinterpret_cast<const uint4*>(&Vt[buf][aOff0 + mi * 512]);
        unsigned vv[4] = {vr.x, vr.y, vr.z, vr.w};
        unsigned pk[4];
        #pragma unroll
        for (int e = 0; e < 4; ++e) {
          const float vlo = __uint_as_float(vv[e] << 16);
          const float vhi = __uint_as_float(vv[e] & 0xFFFF0000u);
          const float xlo = vlo * wreg[2 * e];
          const float xhi = vhi * wreg[2 * e + 1];
          const float glo = xlo * __builtin_amdgcn_rcpf(1.f + __expf(-xlo));
          const float ghi = xhi * __builtin_amdgcn_rcpf(1.f + __expf(-xhi));
          // round-half-up to bf16 and pack: dst = {bf(ghi), bf(glo)}
          pk[e] = __builtin_amdgcn_perm(__float_as_uint(ghi) + 0x8000u,
                                        __float_as_uint(glo) + 0x8000u, 0x07060302u);
        }
        uint4 pr = {pk[0], pk[1], pk[2], pk[3]};
        af[mi] = __builtin_bit_cast(bf16x8, pr);
      }
    }

    #pragma unroll
    for (int ni = 0; ni < 8; ++ni) {
      uint4 br = *reinterpret_cast<const uint4*>(&Btl[buf][bOff0 + ni * 512]);
      bf16x8 bf = __builtin_bit_cast(bf16x8, br);
      acc[0][ni] = __builtin_amdgcn_mfma_f32_16x16x32_bf16(af[0], bf, acc[0][ni], 0, 0, 0);
      acc[1][ni] = __builtin_amdgcn_mfma_f32_16x16x32_bf16(af[1], bf, acc[1][ni], 0, 0, 0);
    }
  }

  // ---- epilogue: C/D col = lane&15 (N), row = quad*4+reg (M) ----
  #pragma unroll
  for (int ni = 0; ni < 8; ++ni) {
    const int d = n0 + ni * 16 + l16;
    const float bv = bias[d];
    #pragma unroll
    for (int mi = 0; mi < 2; ++mi) {
      const int lrow = l0 + wv * 32 + mi * 16 + quad * 4;
      #pragma unroll
      for (int rg = 0; rg < 4; ++rg) {
        out[((size_t)(b * L_DIM + lrow + rg) * 4 + j) * D_DIM + d] = acc[mi][ni][rg] + bv;
      }
    }
  }
}

extern "C" void kernel_launch(void* const* d_in, const int* in_sizes, int n_in,
                              void* d_out, int out_size, void* d_ws, size_t ws_size,
                              hipStream_t stream) {
  const float* x    = (const float*)d_in[0];  // (4,1,2048,512) fp32
  const float* W    = (const float*)d_in[1];  // (4,512) fp32
  const float* P    = (const float*)d_in[2];  // (3072,512) fp32
  const float* bias = (const float*)d_in[3];  // (512,) fp32
  float* out = (float*)d_out;                 // (4,1,8192,512) fp32

  unsigned short* XbfZ = (unsigned short*)d_ws;               // 4*2049*512 shorts = 8.39 MB
  unsigned short* Ball = XbfZ + (size_t)4 * NROWS_X * 512;    // 4*512*2048 shorts = 8.39 MB

  convert_x<<<dim3(1025, 4), 256, 0, stream>>>(x, XbfZ);
  build_B<<<256, 256, 0, stream>>>(P, W, Ball);
  gemm_main<<<1024, 256, 0, stream>>>(XbfZ, Ball, W, bias, out);
}

// Round 6
// 199.884 us; speedup vs baseline: 1.7448x; 1.0437x over previous
//
#include <hip/hip_runtime.h>
#include <cstdint>
#include <cstddef>

// (B,H,L,D,k) = (4,1,2048,512,4), SHIFTS = {1,2,4}
// Folded: out[(b,l,j),d] = sum_c v[c]*Qj[c,d]               (diff, K=512)
//                        + sum_{si,c} silu(v[c]*W[j,(c-s)%512]) * Psilu[si,c,d]  (K=1536)
// v = x[b,l-1] for j<3, x[b,l] for j==3.
// Round 6: BN=512 blocks (silu dup=1), 512 threads, silu pipelined +1 iter into
// LDS At so the K-loop has ONE barrier. V triple-buffered, B double-buffered,
// all staging via global_load_lds w=16 with the proven 0-conflict XOR swizzle.
#define D_DIM 512
#define L_DIM 2048
#define KB_DIM 2048    // 512 diff + 3*512 silu
#define NROWS_X 2049   // per-b rows in XbfZ; row 0 is zeros (the l=-1 pad)

typedef __bf16 bf16x8 __attribute__((ext_vector_type(8)));
typedef float  f32x4  __attribute__((ext_vector_type(4)));

__device__ __forceinline__ unsigned f2bf(float f) {
  unsigned u = __float_as_uint(f);
  u += 0x7FFF + ((u >> 16) & 1);   // RNE
  return u >> 16;
}
__device__ __forceinline__ void gld_lds16(const void* g, void* l) {
  __builtin_amdgcn_global_load_lds((const __attribute__((address_space(1))) void*)g,
                                   (__attribute__((address_space(3))) void*)l,
                                   16, 0, 0);
}

// ---------------- prepass 1: x fp32 -> XbfZ bf16 with per-b zero row at index 0 ----
__global__ void convert_x(const float* __restrict__ x, unsigned short* __restrict__ XbfZ) {
  const int b = blockIdx.y;
  const int idx = blockIdx.x * 256 + threadIdx.x;   // over 2049*128 uint2-groups
  if (idx >= NROWS_X * 128) return;
  const int rr = idx >> 7;       // 0..2048 ; rr==0 -> zero row
  const int c4 = idx & 127;
  uint2 p = {0u, 0u};
  if (rr > 0) {
    float4 v = reinterpret_cast<const float4*>(x)[((size_t)b * L_DIM + rr - 1) * 128 + c4];
    p.x = f2bf(v.x) | (f2bf(v.y) << 16);
    p.y = f2bf(v.z) | (f2bf(v.w) << 16);
  }
  reinterpret_cast<uint2*>(XbfZ)[((size_t)b * NROWS_X + rr) * 128 + c4] = p;
}

// ---------------- prepass 2: build Ball[j][d][k] bf16 (k-major rows) ----------------
__global__ void build_B(const float* __restrict__ P, const float* __restrict__ W,
                        unsigned short* __restrict__ Ball) {
  const int bx = blockIdx.x;             // 256 blocks
  const int j = bx >> 6, dt = (bx >> 3) & 7, ct = bx & 7;
  const int t = threadIdx.x;
  const int d = dt * 64 + (t & 63);
  const int cbase = ct * 64 + (t >> 6) * 16;
  unsigned short bufd[16];
  unsigned short bufs[3][16];
  #pragma unroll
  for (int cc = 0; cc < 16; ++cc) {
    const int c = cbase + cc;
    float qd = 0.f;
    #pragma unroll
    for (int si = 0; si < 3; ++si) {
      const int s = 1 << si;
      const int cm = (c - s) & 511, cp = (c + s) & 511;
      qd += W[j * 512 + cm] * P[((size_t)(2 * si) * 512 + c) * 512 + d]
          - W[j * 512 + cp] * P[((size_t)(2 * si) * 512 + cp) * 512 + d];
      bufs[si][cc] = (unsigned short)f2bf(P[((size_t)(2 * si + 1) * 512 + c) * 512 + d]);
    }
    bufd[cc] = (unsigned short)f2bf(qd);
  }
  unsigned short* row = Ball + (size_t)(j * 512 + d) * KB_DIM;
  *reinterpret_cast<uint4*>(&row[cbase])     = *reinterpret_cast<uint4*>(&bufd[0]);
  *reinterpret_cast<uint4*>(&row[cbase + 8]) = *reinterpret_cast<uint4*>(&bufd[8]);
  #pragma unroll
  for (int si = 0; si < 3; ++si) {
    *reinterpret_cast<uint4*>(&row[512 + si * 512 + cbase])     = *reinterpret_cast<uint4*>(&bufs[si][0]);
    *reinterpret_cast<uint4*>(&row[512 + si * 512 + cbase + 8]) = *reinterpret_cast<uint4*>(&bufs[si][8]);
  }
}

// ---------------- main kernel ----------------
// LDS tile layout (per 128-row x 32-k panel, 4096 shorts): slot s in [0,512) of 16 B.
//   s -> row = 2*(s>>3)+((s>>2)&1), chunk = (s&3)^((s>>3)&3)
// Read (row r, chunk q): addr = (r>>1)*64 + ((q^((r>>1)&3)) + 4*(r&1))*8 shorts.
// Bt spans 512 rows = 4 panels of 4096 shorts.  (Swizzle measured 0-conflict in R5.)
__global__ __launch_bounds__(512, 2) void gemm_main(
    const unsigned short* __restrict__ XbfZ, const unsigned short* __restrict__ Ball,
    const float* __restrict__ W, const float* __restrict__ bias,
    float* __restrict__ out) {
  __shared__ alignas(16) unsigned short Vt[3][4096];    // 24 KB (triple buffer)
  __shared__ alignas(16) unsigned short Btl[2][16384];  // 64 KB
  __shared__ alignas(16) unsigned short At[2][4096];    // 16 KB (silu tile, pipelined)
  __shared__ alignas(16) float Wr[1536];                //  6 KB

  const int tid = threadIdx.x;
  // XCD-aware decode: blocks on one XCD share j -> 2 MB Ball slice L2-resident
  const int xcd = blockIdx.x & 7, slot = blockIdx.x >> 3;
  const int j = xcd >> 1;
  const int sub = ((xcd & 1) << 5) | slot;   // 0..63
  const int b = sub >> 4;
  const int l0 = (sub & 15) * 128;

  // ---- stage rolled W (fp32): Wr[si*512+c] = W[j, (c - 2^si) mod 512] ----
  #pragma unroll
  for (int i = 0; i < 3; ++i) {
    const int idx = tid + i * 512;
    const int si = idx >> 9, c = idx & 511;
    Wr[idx] = W[j * 512 + ((c - (1 << si)) & 511)];
  }

  // ---- staging geometry: thread <-> slot tid ----
  const int row1 = 2 * (tid >> 3) + ((tid >> 2) & 1);   // 0..127
  const int q1   = (tid & 3) ^ ((tid >> 3) & 3);        // chunk 0..3
  const unsigned short* srcV =
      XbfZ + ((size_t)b * NROWS_X + l0 + (j == 3) + row1) * 512 + q1 * 8;
  const unsigned short* srcB =
      Ball + ((size_t)j * 512 + row1) * KB_DIM + q1 * 8;  // + k*262144 per 128-row panel

  // ---- fragment geometry: 8 waves as 2M x 4N, wave-tile 64M x 128N ----
  const int lane = tid & 63, wv = tid >> 6;
  const int wm = wv >> 2, wn = wv & 3;
  const int l16 = lane & 15, quad = lane >> 4;
  const int posf = ((quad ^ ((l16 >> 1) & 3)) + 4 * (l16 & 1)) * 8;
  const int aOffFrag = wm * 2048 + (l16 >> 1) * 64 + posf;   // + mi*512
  const int bOffFrag = wn * 4096 + (l16 >> 1) * 64 + posf;   // + ni*512

  f32x4 acc[4][8];
  #pragma unroll
  for (int i = 0; i < 4; ++i)
    #pragma unroll
    for (int n = 0; n < 8; ++n)
      acc[i][n] = f32x4{0.f, 0.f, 0.f, 0.f};

  // ---- prologue: V(0), V(1), B(0) ----
  gld_lds16(srcV,      &Vt[0][tid * 8]);
  gld_lds16(srcV + 32, &Vt[1][tid * 8]);
  #pragma unroll
  for (int k = 0; k < 4; ++k)
    gld_lds16(srcB + (size_t)k * 262144, &Btl[0][k * 4096 + tid * 8]);

  int vA = 0, vB = 1, vC = 2;  // frag-read / silu-read / landing
  for (int it = 0; it < 64; ++it) {
    __syncthreads();   // single barrier: seals V(it),V(it+1),B(it),At(it)

    // prefetch (issued AFTER barrier -> full compute phase to land)
    if (it < 62)
      gld_lds16(srcV + ((it + 2) & 15) * 32, &Vt[vC][tid * 8]);
    if (it < 63) {
      const int ko = (it + 1) * 32;
      #pragma unroll
      for (int k = 0; k < 4; ++k)
        gld_lds16(srcB + (size_t)k * 262144 + ko,
                  &Btl[(it + 1) & 1][k * 4096 + tid * 8]);
    }

    // silu for iter it+1 (reads V(it+1) staged 2 iters ago, writes At[(it+1)&1])
    if (it >= 15 && it < 63) {
      const int itn = it + 1;
      const int si = (itn >> 4) - 1;
      const int kwin = (itn * 32) & 511;
      uint4 vr = *reinterpret_cast<const uint4*>(&Vt[vB][tid * 8]);
      const float* wp = &Wr[si * 512 + kwin + q1 * 8];
      const float4 wa4 = *reinterpret_cast<const float4*>(wp);
      const float4 wb4 = *reinterpret_cast<const float4*>(wp + 4);
      const float wreg[8] = {wa4.x, wa4.y, wa4.z, wa4.w, wb4.x, wb4.y, wb4.z, wb4.w};
      unsigned vv[4] = {vr.x, vr.y, vr.z, vr.w};
      unsigned pk[4];
      #pragma unroll
      for (int e = 0; e < 4; ++e) {
        const float vlo = __uint_as_float(vv[e] << 16);
        const float vhi = __uint_as_float(vv[e] & 0xFFFF0000u);
        const float xlo = vlo * wreg[2 * e];
        const float xhi = vhi * wreg[2 * e + 1];
        const float glo = xlo * __builtin_amdgcn_rcpf(1.f + __expf(-xlo));
        const float ghi = xhi * __builtin_amdgcn_rcpf(1.f + __expf(-xhi));
        pk[e] = __builtin_amdgcn_perm(__float_as_uint(ghi) + 0x8000u,
                                      __float_as_uint(glo) + 0x8000u, 0x07060302u);
      }
      uint4 pr = {pk[0], pk[1], pk[2], pk[3]};
      *reinterpret_cast<uint4*>(&At[itn & 1][tid * 8]) = pr;
    }

    // fragments + MFMA (A: diff iters from Vt[vA], silu iters from At[it&1])
    const unsigned short* aSrc = (it < 16) ? &Vt[vA][0] : &At[it & 1][0];
    const unsigned short* bSrc = &Btl[it & 1][0];
    bf16x8 bfr[8];
    #pragma unroll
    for (int ni = 0; ni < 8; ++ni) {
      uint4 br = *reinterpret_cast<const uint4*>(&bSrc[bOffFrag + ni * 512]);
      bfr[ni] = __builtin_bit_cast(bf16x8, br);
    }
    #pragma unroll
    for (int mi = 0; mi < 4; ++mi) {
      uint4 ar = *reinterpret_cast<const uint4*>(&aSrc[aOffFrag + mi * 512]);
      bf16x8 af = __builtin_bit_cast(bf16x8, ar);
      #pragma unroll
      for (int ni = 0; ni < 8; ++ni)
        acc[mi][ni] = __builtin_amdgcn_mfma_f32_16x16x32_bf16(af, bfr[ni], acc[mi][ni], 0, 0, 0);
    }

    const int t = vA; vA = vB; vB = vC; vC = t;   // rotate V buffers
  }

  // ---- epilogue: C/D col = lane&15 (N), row = quad*4+reg (M) ----
  #pragma unroll
  for (int ni = 0; ni < 8; ++ni) {
    const int d = wn * 128 + ni * 16 + l16;
    const float bv = bias[d];
    #pragma unroll
    for (int mi = 0; mi < 4; ++mi) {
      const int lrow = l0 + wm * 64 + mi * 16 + quad * 4;
      #pragma unroll
      for (int rg = 0; rg < 4; ++rg) {
        out[((size_t)(b * L_DIM + lrow + rg) * 4 + j) * D_DIM + d] = acc[mi][ni][rg] + bv;
      }
    }
  }
}

extern "C" void kernel_launch(void* const* d_in, const int* in_sizes, int n_in,
                              void* d_out, int out_size, void* d_ws, size_t ws_size,
                              hipStream_t stream) {
  const float* x    = (const float*)d_in[0];  // (4,1,2048,512) fp32
  const float* W    = (const float*)d_in[1];  // (4,512) fp32
  const float* P    = (const float*)d_in[2];  // (3072,512) fp32
  const float* bias = (const float*)d_in[3];  // (512,) fp32
  float* out = (float*)d_out;                 // (4,1,8192,512) fp32

  unsigned short* XbfZ = (unsigned short*)d_ws;               // 4*2049*512 shorts = 8.39 MB
  unsigned short* Ball = XbfZ + (size_t)4 * NROWS_X * 512;    // 4*512*2048 shorts = 8.39 MB

  convert_x<<<dim3(1025, 4), 256, 0, stream>>>(x, XbfZ);
  build_B<<<256, 256, 0, stream>>>(P, W, Ball);
  gemm_main<<<256, 512, 0, stream>>>(XbfZ, Ball, W, bias, out);
}